// Round 1
// baseline (760.985 us; speedup 1.0000x reference)
//
#include <hip/hip_runtime.h>

typedef __bf16 bf16_t;
typedef __bf16 bf16x8 __attribute__((ext_vector_type(8)));
typedef float f32x4 __attribute__((ext_vector_type(4)));

#define DM 768
#define SEQ_LEN 4096
#define TOKENS 32768

// ---------------- weight cast / transpose ----------------
// WT[n*K + k] = bf16(W[k*N + n])   (store weights N-major so GEMM B-operand
// fragments are contiguous along K)
__global__ __launch_bounds__(256)
void cast_transpose_kernel(const float* __restrict__ W, bf16_t* __restrict__ WT,
                           int K, int N) {
  long idx = (long)blockIdx.x * 256 + threadIdx.x;
  if (idx >= (long)K * N) return;
  int n = (int)(idx / K);
  int k = (int)(idx % K);
  WT[idx] = (bf16_t)W[(long)k * N + n];
}

// w_x_ext transposed: rows n in [0,832), cols k in [0,768)
//  n <  16  : A[k][n]   = -exp(A_log[k*16+n])      (for hA)
//  16<=n<32 : W_x[k][n-16]                         (Bm columns)
//  32<=n<800: W_x[k][n-16]                         (Cm columns, ref cols 16..783)
//  n >= 800 : 0 (pad so GEMM N=832 is a multiple of 64 -> no bounds checks)
__global__ __launch_bounds__(256)
void build_wx_kernel(const float* __restrict__ Wx, const float* __restrict__ A_log,
                     bf16_t* __restrict__ WT) {
  long idx = (long)blockIdx.x * 256 + threadIdx.x;
  if (idx >= (long)832 * 768) return;
  int n = (int)(idx / 768);
  int k = (int)(idx % 768);
  float v;
  if (n < 16)        v = -expf(A_log[k * 16 + n]);
  else if (n < 800)  v = Wx[(long)k * 784 + (n - 16)];
  else               v = 0.f;
  WT[idx] = (bf16_t)v;
}

// ---------------- layernorm -> bf16 ----------------
__global__ __launch_bounds__(256)
void ln_kernel(const float* __restrict__ x, const float* __restrict__ gamma,
               const float* __restrict__ beta, bf16_t* __restrict__ xn) {
  const int tok = blockIdx.x;
  const int t = threadIdx.x;
  const float* xr = x + (long)tok * DM;
  float v0 = xr[t], v1 = xr[t + 256], v2 = xr[t + 512];
  float s = v0 + v1 + v2;
  float ss = v0 * v0 + v1 * v1 + v2 * v2;
  for (int o = 32; o > 0; o >>= 1) { s += __shfl_down(s, o); ss += __shfl_down(ss, o); }
  __shared__ float rs[4], rss[4];
  if ((t & 63) == 0) { rs[t >> 6] = s; rss[t >> 6] = ss; }
  __syncthreads();
  float S = rs[0] + rs[1] + rs[2] + rs[3];
  float SS = rss[0] + rss[1] + rss[2] + rss[3];
  float mu = S * (1.0f / DM);
  float var = SS * (1.0f / DM) - mu * mu;
  float inv = rsqrtf(var + 1e-5f);
  bf16_t* xo = xn + (long)tok * DM;
  xo[t]       = (bf16_t)((v0 - mu) * inv * gamma[t] + beta[t]);
  xo[t + 256] = (bf16_t)((v1 - mu) * inv * gamma[t + 256] + beta[t + 256]);
  xo[t + 512] = (bf16_t)((v2 - mu) * inv * gamma[t + 512] + beta[t + 512]);
}

// ---------------- depthwise causal conv (4 taps) ----------------
// x1[tok][c] = sum_k w[c][k] * x1_pre[tok-3+k][c], zero-padded at sequence start.
// x1_pre lives in xz columns 0..767 (row stride 1536).
__global__ __launch_bounds__(256)
void conv_kernel(const bf16_t* __restrict__ xz, const float* __restrict__ conv_w,
                 bf16_t* __restrict__ x1) {
  const int tok = blockIdx.x;
  const int l = tok & (SEQ_LEN - 1);
  const int t = threadIdx.x;
#pragma unroll
  for (int i = 0; i < 3; i++) {
    const int c = t + i * 256;
    const bf16_t* base = xz + (long)tok * 1536 + c;
    float w0 = conv_w[c * 4 + 0], w1 = conv_w[c * 4 + 1];
    float w2 = conv_w[c * 4 + 2], w3 = conv_w[c * 4 + 3];
    float acc = w3 * (float)base[0];
    if (l >= 1) acc += w2 * (float)base[-1536];
    if (l >= 2) acc += w1 * (float)base[-2 * 1536];
    if (l >= 3) acc += w0 * (float)base[-3 * 1536];
    x1[(long)tok * DM + c] = (bf16_t)acc;
  }
}

// ---------------- per-token SSM elementwise ----------------
// ssm row layout (stride 832): [0..15]=hA, [16..31]=Bm, [32..799]=Cm
// s  = sum_c x1[c]
// hs = sum_d (hA[d] + Bm[d]*s)
// y[c] = (Cm[c]*hs + Dp[c]*x1[c]) * silu(z[c])
__global__ __launch_bounds__(256)
void ssm_ew_kernel(const bf16_t* __restrict__ x1, const float* __restrict__ ssm,
                   const bf16_t* __restrict__ xz, const float* __restrict__ Dp,
                   bf16_t* __restrict__ y) {
  const int tok = blockIdx.x;
  const int t = threadIdx.x;
  const bf16_t* x1r = x1 + (long)tok * DM;
  const float* sr = ssm + (long)tok * 832;
  float xv0 = (float)x1r[t], xv1 = (float)x1r[t + 256], xv2 = (float)x1r[t + 512];
  float s = xv0 + xv1 + xv2;
  for (int o = 32; o > 0; o >>= 1) s += __shfl_down(s, o);
  __shared__ float rs[4];
  if ((t & 63) == 0) rs[t >> 6] = s;
  __syncthreads();
  float S = rs[0] + rs[1] + rs[2] + rs[3];
  float hs = 0.f;
#pragma unroll
  for (int d = 0; d < 16; d++) hs += sr[d] + sr[16 + d] * S;
  const bf16_t* zr = xz + (long)tok * 1536 + 768;
  bf16_t* yr = y + (long)tok * DM;
#pragma unroll
  for (int i = 0; i < 3; i++) {
    int c = t + i * 256;
    float xv = (i == 0) ? xv0 : (i == 1) ? xv1 : xv2;
    float yv = sr[32 + c] * hs + Dp[c] * xv;
    float zv = (float)zr[c];
    yv *= zv / (1.f + __expf(-zv));
    yr[c] = (bf16_t)yv;
  }
}

// ---------------- bf16 MFMA GEMM: C[M,N] = A[M,K] @ BT[N,K]^T ----------------
// OUT_MODE: 0 -> bf16 out, 1 -> f32 out, 2 -> f32 out + residual add
template <int OUT_MODE>
__global__ __launch_bounds__(256)
void gemm_bt_kernel(const bf16_t* __restrict__ A, const bf16_t* __restrict__ BT,
                    void* __restrict__ outp, const float* __restrict__ res,
                    int M, int N, int K) {
  __shared__ __align__(16) bf16_t As[64][40];  // +8 pad: 80B rows -> conflict-free-ish
  __shared__ __align__(16) bf16_t Bs[64][40];
  const int m0 = blockIdx.x * 64;
  const int n0 = blockIdx.y * 64;
  const int t = threadIdx.x;
  const int lane = t & 63;
  const int wave = t >> 6;
  const int wm = (wave >> 1) * 32;
  const int wn = (wave & 1) * 32;
  const int l15 = lane & 15;
  const int quad = lane >> 4;

  f32x4 acc[2][2] = {};

  const int ar = t >> 2;          // 0..63 : tile row
  const int ak = (t & 3) * 8;     // 0,8,16,24 : k offset (16B per thread)
  const bf16_t* Ag = A + (long)(m0 + ar) * K + ak;
  const bf16_t* Bg = BT + (long)(n0 + ar) * K + ak;

  for (int k0 = 0; k0 < K; k0 += 32) {
    *(bf16x8*)&As[ar][ak] = *(const bf16x8*)(Ag + k0);
    *(bf16x8*)&Bs[ar][ak] = *(const bf16x8*)(Bg + k0);
    __syncthreads();
    bf16x8 a0 = *(const bf16x8*)&As[wm + l15][quad * 8];
    bf16x8 a1 = *(const bf16x8*)&As[wm + 16 + l15][quad * 8];
    bf16x8 b0 = *(const bf16x8*)&Bs[wn + l15][quad * 8];
    bf16x8 b1 = *(const bf16x8*)&Bs[wn + 16 + l15][quad * 8];
    acc[0][0] = __builtin_amdgcn_mfma_f32_16x16x32_bf16(a0, b0, acc[0][0], 0, 0, 0);
    acc[0][1] = __builtin_amdgcn_mfma_f32_16x16x32_bf16(a0, b1, acc[0][1], 0, 0, 0);
    acc[1][0] = __builtin_amdgcn_mfma_f32_16x16x32_bf16(a1, b0, acc[1][0], 0, 0, 0);
    acc[1][1] = __builtin_amdgcn_mfma_f32_16x16x32_bf16(a1, b1, acc[1][1], 0, 0, 0);
    __syncthreads();
  }

#pragma unroll
  for (int mi = 0; mi < 2; mi++)
#pragma unroll
    for (int ni = 0; ni < 2; ni++)
#pragma unroll
      for (int r = 0; r < 4; r++) {
        int row = m0 + wm + mi * 16 + quad * 4 + r;
        int col = n0 + wn + ni * 16 + l15;
        long o = (long)row * N + col;
        float v = acc[mi][ni][r];
        if (OUT_MODE == 0)      ((bf16_t*)outp)[o] = (bf16_t)v;
        else if (OUT_MODE == 1) ((float*)outp)[o] = v;
        else                    ((float*)outp)[o] = v + res[o];
      }
}

// ---------------- launch ----------------
extern "C" void kernel_launch(void* const* d_in, const int* in_sizes, int n_in,
                              void* d_out, int out_size, void* d_ws, size_t ws_size,
                              hipStream_t stream) {
  const float* x      = (const float*)d_in[0];
  const float* W_in   = (const float*)d_in[1];
  const float* conv_w = (const float*)d_in[2];
  const float* W_x    = (const float*)d_in[3];
  const float* A_log  = (const float*)d_in[4];
  const float* Dp     = (const float*)d_in[5];
  const float* W_out  = (const float*)d_in[6];
  const float* gamma  = (const float*)d_in[7];
  const float* beta   = (const float*)d_in[8];
  float* out = (float*)d_out;

  char* ws = (char*)d_ws;
  // offsets (bytes)
  bf16_t* w_in_T  = (bf16_t*)(ws + 0);          // 1536x768 bf16 = 2359296
  bf16_t* w_x_T   = (bf16_t*)(ws + 2359296);    //  832x768 bf16 = 1277952
  bf16_t* w_out_T = (bf16_t*)(ws + 3637248);    //  768x768 bf16 = 1179648
  bf16_t* xn      = (bf16_t*)(ws + 4816896);    // 32768x768 bf16 = 50331648 (reused as y)
  bf16_t* xz      = (bf16_t*)(ws + 55148544);   // 32768x1536 bf16 = 100663296
  bf16_t* x1      = (bf16_t*)(ws + 155811840);  // 32768x768 bf16 = 50331648
  float*  ssm     = (float*)(ws + 206143488);   // 32768x832 f32 = 109051904
  bf16_t* y       = xn;                         // xn dead after GEMM1

  // weights -> bf16 transposed (must be redone every call: inputs re-poisoned)
  cast_transpose_kernel<<<dim3(1536 * 768 / 256), 256, 0, stream>>>(W_in, w_in_T, 768, 1536);
  build_wx_kernel<<<dim3(832 * 768 / 256), 256, 0, stream>>>(W_x, A_log, w_x_T);
  cast_transpose_kernel<<<dim3(768 * 768 / 256), 256, 0, stream>>>(W_out, w_out_T, 768, 768);

  // layernorm
  ln_kernel<<<dim3(TOKENS), 256, 0, stream>>>(x, gamma, beta, xn);

  // xz = xn @ W_in  (bf16 out)
  gemm_bt_kernel<0><<<dim3(TOKENS / 64, 1536 / 64), 256, 0, stream>>>(
      xn, w_in_T, (void*)xz, nullptr, TOKENS, 1536, 768);

  // depthwise causal conv over x1 part of xz
  conv_kernel<<<dim3(TOKENS), 256, 0, stream>>>(xz, conv_w, x1);

  // ssm = x1 @ [A | Wx_B | Wx_C | pad]  (f32 out, N=832)
  gemm_bt_kernel<1><<<dim3(TOKENS / 64, 832 / 64), 256, 0, stream>>>(
      x1, w_x_T, (void*)ssm, nullptr, TOKENS, 832, 768);

  // per-token ssm math + silu gate -> y (bf16)
  ssm_ew_kernel<<<dim3(TOKENS), 256, 0, stream>>>(x1, ssm, xz, Dp, y);

  // out = y @ W_out + residual (f32)
  gemm_bt_kernel<2><<<dim3(TOKENS / 64, 768 / 64), 256, 0, stream>>>(
      y, w_out_T, (void*)out, x, TOKENS, 768, 768);
}

// Round 2
// 603.851 us; speedup vs baseline: 1.2602x; 1.2602x over previous
//
#include <hip/hip_runtime.h>

typedef __bf16 bf16_t;
typedef __bf16 bf16x8 __attribute__((ext_vector_type(8)));
typedef float f32x4 __attribute__((ext_vector_type(4)));

#define DM 768
#define SEQ_LEN 4096
#define TOKENS 32768

// async 16B global -> LDS (wave-uniform LDS base + lane*16)
__device__ __forceinline__ void load16_to_lds(const void* g, void* l) {
  __builtin_amdgcn_global_load_lds(
      (const __attribute__((address_space(1))) unsigned int*)g,
      (__attribute__((address_space(3))) unsigned int*)l, 16, 0, 0);
}

// ---------------- weight cast / transpose ----------------
// WT[n*K + k] = bf16(W[k*stride + off + n])
__global__ __launch_bounds__(256)
void cast_transpose_kernel(const float* __restrict__ W, bf16_t* __restrict__ WT,
                           int K, int N, int stride, int off) {
  long idx = (long)blockIdx.x * 256 + threadIdx.x;
  if (idx >= (long)K * N) return;
  int n = (int)(idx / K);
  int k = (int)(idx % K);
  WT[idx] = (bf16_t)W[(long)k * stride + off + n];
}

// a[k] = -sum_d exp(A_log[k,d]) ; b[k] = sum_{d<16} W_x[k,d]
__global__ __launch_bounds__(256)
void ab_kernel(const float* __restrict__ Wx, const float* __restrict__ A_log,
               float* __restrict__ a_vec, float* __restrict__ b_vec) {
  int k = blockIdx.x * 256 + threadIdx.x;
  if (k >= DM) return;
  float a = 0.f, b = 0.f;
#pragma unroll
  for (int d = 0; d < 16; d++) {
    a -= __expf(A_log[k * 16 + d]);
    b += Wx[(long)k * 784 + d];
  }
  a_vec[k] = a;
  b_vec[k] = b;
}

// ---------------- layernorm -> bf16 ----------------
__global__ __launch_bounds__(256)
void ln_kernel(const float* __restrict__ x, const float* __restrict__ gamma,
               const float* __restrict__ beta, bf16_t* __restrict__ xn) {
  const int tok = blockIdx.x;
  const int t = threadIdx.x;
  const float* xr = x + (long)tok * DM;
  float v0 = xr[t], v1 = xr[t + 256], v2 = xr[t + 512];
  float s = v0 + v1 + v2;
  float ss = v0 * v0 + v1 * v1 + v2 * v2;
  for (int o = 32; o > 0; o >>= 1) { s += __shfl_down(s, o); ss += __shfl_down(ss, o); }
  __shared__ float rs[4], rss[4];
  if ((t & 63) == 0) { rs[t >> 6] = s; rss[t >> 6] = ss; }
  __syncthreads();
  float S = rs[0] + rs[1] + rs[2] + rs[3];
  float SS = rss[0] + rss[1] + rss[2] + rss[3];
  float mu = S * (1.0f / DM);
  float var = SS * (1.0f / DM) - mu * mu;
  float inv = rsqrtf(var + 1e-5f);
  bf16_t* xo = xn + (long)tok * DM;
  xo[t]       = (bf16_t)((v0 - mu) * inv * gamma[t] + beta[t]);
  xo[t + 256] = (bf16_t)((v1 - mu) * inv * gamma[t + 256] + beta[t + 256]);
  xo[t + 512] = (bf16_t)((v2 - mu) * inv * gamma[t + 512] + beta[t + 512]);
}

// ---------------- depthwise causal conv (4 taps) + hs reduction ----------------
// x1[tok][c] = conv(x1_pre) ; hs[tok] = x1·a + (x1·1)*(x1·b)
__global__ __launch_bounds__(256)
void conv_kernel(const bf16_t* __restrict__ xz, const float* __restrict__ conv_w,
                 const float* __restrict__ a_vec, const float* __restrict__ b_vec,
                 bf16_t* __restrict__ x1, float* __restrict__ hs) {
  const int tok = blockIdx.x;
  const int l = tok & (SEQ_LEN - 1);
  const int t = threadIdx.x;
  float s = 0.f, sa = 0.f, sb = 0.f;
#pragma unroll
  for (int i = 0; i < 3; i++) {
    const int c = t + i * 256;
    const bf16_t* base = xz + (long)tok * 1536 + c;
    float w0 = conv_w[c * 4 + 0], w1 = conv_w[c * 4 + 1];
    float w2 = conv_w[c * 4 + 2], w3 = conv_w[c * 4 + 3];
    float acc = w3 * (float)base[0];
    if (l >= 1) acc += w2 * (float)base[-1536];
    if (l >= 2) acc += w1 * (float)base[-2 * 1536];
    if (l >= 3) acc += w0 * (float)base[-3 * 1536];
    bf16_t xb = (bf16_t)acc;
    x1[(long)tok * DM + c] = xb;
    float xv = (float)xb;
    s += xv; sa += xv * a_vec[c]; sb += xv * b_vec[c];
  }
  for (int o = 32; o > 0; o >>= 1) {
    s += __shfl_down(s, o); sa += __shfl_down(sa, o); sb += __shfl_down(sb, o);
  }
  __shared__ float rs[4], ra[4], rb[4];
  if ((t & 63) == 0) { rs[t >> 6] = s; ra[t >> 6] = sa; rb[t >> 6] = sb; }
  __syncthreads();
  if (t == 0) {
    float S = rs[0] + rs[1] + rs[2] + rs[3];
    float SA = ra[0] + ra[1] + ra[2] + ra[3];
    float SB = rb[0] + rb[1] + rb[2] + rb[3];
    hs[tok] = SA + S * SB;
  }
}

// ---------------- 128x128 MFMA GEMM (m97 recipe) ----------------
// C[M,N] = A[M,K] @ BT[N,K]^T
// OUT_MODE 0: bf16 out
// OUT_MODE 1: fused SSM epilogue -> y bf16: y = silu(z)*(acc*hs[row] + Dp[col]*x1[row,col])
// OUT_MODE 2: f32 out + residual add
template <int OUT_MODE>
__global__ __launch_bounds__(256)
void gemm128_kernel(const bf16_t* __restrict__ A, const bf16_t* __restrict__ BT,
                    void* __restrict__ outp, const float* __restrict__ res,
                    const bf16_t* __restrict__ x1, const bf16_t* __restrict__ xz,
                    const float* __restrict__ hs, const float* __restrict__ Dp,
                    int M, int N, int K) {
  __shared__ __align__(16) bf16_t As[128 * 32];
  __shared__ __align__(16) bf16_t Bs[128 * 32];
  const int m0 = blockIdx.x * 128;
  const int n0 = blockIdx.y * 128;
  const int t = threadIdx.x;
  const int lane = t & 63;
  const int wave = t >> 6;
  const int wm = (wave >> 1) * 64;
  const int wn = (wave & 1) * 64;
  const int l15 = lane & 15;
  const int quad = lane >> 4;

  f32x4 acc[4][4] = {};

  // staging: chunk = wave*2 + i ; elem = chunk*512 + lane*8 ; row=elem/32, col=elem%32
  const int e0 = wave * 1024 + lane * 8;
  const int r0 = e0 >> 5, c0 = e0 & 31;
  const int r1 = (e0 + 512) >> 5, c1 = (e0 + 512) & 31;
  const bf16_t* Ag0 = A + (long)(m0 + r0) * K + c0;
  const bf16_t* Ag1 = A + (long)(m0 + r1) * K + c1;
  const bf16_t* Bg0 = BT + (long)(n0 + r0) * K + c0;
  const bf16_t* Bg1 = BT + (long)(n0 + r1) * K + c1;
  bf16_t* lA0 = As + wave * 1024;          // wave-uniform LDS bases
  bf16_t* lA1 = As + wave * 1024 + 512;
  bf16_t* lB0 = Bs + wave * 1024;
  bf16_t* lB1 = Bs + wave * 1024 + 512;

  for (int k0 = 0; k0 < K; k0 += 32) {
    load16_to_lds(Ag0 + k0, lA0);
    load16_to_lds(Ag1 + k0, lA1);
    load16_to_lds(Bg0 + k0, lB0);
    load16_to_lds(Bg1 + k0, lB1);
    __syncthreads();
    bf16x8 af[4], bf[4];
#pragma unroll
    for (int mi = 0; mi < 4; mi++)
      af[mi] = *(const bf16x8*)&As[(wm + mi * 16 + l15) * 32 + quad * 8];
#pragma unroll
    for (int ni = 0; ni < 4; ni++)
      bf[ni] = *(const bf16x8*)&Bs[(wn + ni * 16 + l15) * 32 + quad * 8];
#pragma unroll
    for (int mi = 0; mi < 4; mi++)
#pragma unroll
      for (int ni = 0; ni < 4; ni++)
        acc[mi][ni] = __builtin_amdgcn_mfma_f32_16x16x32_bf16(af[mi], bf[ni], acc[mi][ni], 0, 0, 0);
    __syncthreads();
  }

#pragma unroll
  for (int mi = 0; mi < 4; mi++) {
#pragma unroll
    for (int r = 0; r < 4; r++) {
      const int row = m0 + wm + mi * 16 + quad * 4 + r;
      float hsv = 0.f;
      if (OUT_MODE == 1) hsv = hs[row];
#pragma unroll
      for (int ni = 0; ni < 4; ni++) {
        const int col = n0 + wn + ni * 16 + l15;
        const long o = (long)row * N + col;
        float v = acc[mi][ni][r];
        if (OUT_MODE == 0) {
          ((bf16_t*)outp)[o] = (bf16_t)v;
        } else if (OUT_MODE == 1) {
          float xv = (float)x1[(long)row * DM + col];
          float zv = (float)xz[(long)row * 1536 + DM + col];
          float yv = v * hsv + Dp[col] * xv;
          yv *= zv / (1.f + __expf(-zv));
          ((bf16_t*)outp)[o] = (bf16_t)yv;
        } else {
          ((float*)outp)[o] = v + res[o];
        }
      }
    }
  }
}

// ---------------- launch ----------------
extern "C" void kernel_launch(void* const* d_in, const int* in_sizes, int n_in,
                              void* d_out, int out_size, void* d_ws, size_t ws_size,
                              hipStream_t stream) {
  const float* x      = (const float*)d_in[0];
  const float* W_in   = (const float*)d_in[1];
  const float* conv_w = (const float*)d_in[2];
  const float* W_x    = (const float*)d_in[3];
  const float* A_log  = (const float*)d_in[4];
  const float* Dp     = (const float*)d_in[5];
  const float* W_out  = (const float*)d_in[6];
  const float* gamma  = (const float*)d_in[7];
  const float* beta   = (const float*)d_in[8];
  float* out = (float*)d_out;

  char* ws = (char*)d_ws;
  bf16_t* w_in_T  = (bf16_t*)(ws + 0);          // 1536x768 bf16 = 2359296 B
  bf16_t* w_c_T   = (bf16_t*)(ws + 2359296);    //  768x768 bf16 = 1179648 B
  bf16_t* w_out_T = (bf16_t*)(ws + 3538944);    //  768x768 bf16 = 1179648 B
  float*  a_vec   = (float*)(ws + 4718592);     //  768 f32
  float*  b_vec   = (float*)(ws + 4721664);     //  768 f32
  float*  hs      = (float*)(ws + 4724736);     //  32768 f32 = 131072 B
  bf16_t* xn      = (bf16_t*)(ws + 4855808);    // 32768x768 bf16 = 50331648 B (reused as y)
  bf16_t* xz      = (bf16_t*)(ws + 55187456);   // 32768x1536 bf16 = 100663296 B
  bf16_t* x1      = (bf16_t*)(ws + 155850752);  // 32768x768 bf16 = 50331648 B
  bf16_t* y       = xn;                         // xn dead after GEMM1

  // weight prep (re-done every call: inputs re-poisoned)
  cast_transpose_kernel<<<dim3(1536 * 768 / 256), 256, 0, stream>>>(W_in, w_in_T, 768, 1536, 1536, 0);
  cast_transpose_kernel<<<dim3(768 * 768 / 256), 256, 0, stream>>>(W_x, w_c_T, 768, 768, 784, 16);
  cast_transpose_kernel<<<dim3(768 * 768 / 256), 256, 0, stream>>>(W_out, w_out_T, 768, 768, 768, 0);
  ab_kernel<<<dim3(3), 256, 0, stream>>>(W_x, A_log, a_vec, b_vec);

  // layernorm
  ln_kernel<<<dim3(TOKENS), 256, 0, stream>>>(x, gamma, beta, xn);

  // xz = xn @ W_in
  gemm128_kernel<0><<<dim3(TOKENS / 128, 1536 / 128), 256, 0, stream>>>(
      xn, w_in_T, (void*)xz, nullptr, nullptr, nullptr, nullptr, nullptr,
      TOKENS, 1536, 768);

  // depthwise causal conv + hs
  conv_kernel<<<dim3(TOKENS), 256, 0, stream>>>(xz, conv_w, a_vec, b_vec, x1, hs);

  // y = silu(z) * (hs * (x1 @ Wc) + Dp * x1)
  gemm128_kernel<1><<<dim3(TOKENS / 128, 768 / 128), 256, 0, stream>>>(
      x1, w_c_T, (void*)y, nullptr, x1, xz, hs, Dp,
      TOKENS, 768, 768);

  // out = y @ W_out + residual
  gemm128_kernel<2><<<dim3(TOKENS / 128, 768 / 128), 256, 0, stream>>>(
      y, w_out_T, (void*)out, x, nullptr, nullptr, nullptr, nullptr,
      TOKENS, 768, 768);
}

// Round 3
// 532.696 us; speedup vs baseline: 1.4286x; 1.1336x over previous
//
#include <hip/hip_runtime.h>

typedef __bf16 bf16_t;
typedef __bf16 bf16x8 __attribute__((ext_vector_type(8)));
typedef __bf16 bf16x4 __attribute__((ext_vector_type(4)));
typedef float f32x4 __attribute__((ext_vector_type(4)));

#define DM 768
#define SEQ_LEN 4096
#define TOKENS 32768

// async 16B global -> LDS (wave-uniform LDS base + lane*16)
__device__ __forceinline__ void load16_to_lds(const void* g, void* l) {
  __builtin_amdgcn_global_load_lds(
      (const __attribute__((address_space(1))) unsigned int*)g,
      (__attribute__((address_space(3))) unsigned int*)l, 16, 0, 0);
}

// ---------------- weight cast / transpose ----------------
__global__ __launch_bounds__(256)
void cast_transpose_kernel(const float* __restrict__ W, bf16_t* __restrict__ WT,
                           int K, int N, int stride, int off) {
  long idx = (long)blockIdx.x * 256 + threadIdx.x;
  if (idx >= (long)K * N) return;
  int n = (int)(idx / K);
  int k = (int)(idx % K);
  WT[idx] = (bf16_t)W[(long)k * stride + off + n];
}

// a[k] = -sum_d exp(A_log[k,d]) ; b[k] = sum_{d<16} W_x[k,d]
__global__ __launch_bounds__(256)
void ab_kernel(const float* __restrict__ Wx, const float* __restrict__ A_log,
               float* __restrict__ a_vec, float* __restrict__ b_vec) {
  int k = blockIdx.x * 256 + threadIdx.x;
  if (k >= DM) return;
  float a = 0.f, b = 0.f;
#pragma unroll
  for (int d = 0; d < 16; d++) {
    a -= __expf(A_log[k * 16 + d]);
    b += Wx[(long)k * 784 + d];
  }
  a_vec[k] = a;
  b_vec[k] = b;
}

// ---------------- layernorm -> bf16 (token per wave, float4) ----------------
__global__ __launch_bounds__(256)
void ln_kernel(const float* __restrict__ x, const float* __restrict__ gamma,
               const float* __restrict__ beta, bf16_t* __restrict__ xn) {
  const int tok = blockIdx.x * 4 + (threadIdx.x >> 6);
  const int lane = threadIdx.x & 63;
  const float4* xr = (const float4*)(x + (long)tok * DM);
  float4 v0 = xr[lane], v1 = xr[lane + 64], v2 = xr[lane + 128];
  float s = v0.x + v0.y + v0.z + v0.w + v1.x + v1.y + v1.z + v1.w +
            v2.x + v2.y + v2.z + v2.w;
  float ss = v0.x * v0.x + v0.y * v0.y + v0.z * v0.z + v0.w * v0.w +
             v1.x * v1.x + v1.y * v1.y + v1.z * v1.z + v1.w * v1.w +
             v2.x * v2.x + v2.y * v2.y + v2.z * v2.z + v2.w * v2.w;
  for (int o = 1; o < 64; o <<= 1) { s += __shfl_xor(s, o); ss += __shfl_xor(ss, o); }
  float mu = s * (1.0f / DM);
  float var = ss * (1.0f / DM) - mu * mu;
  float inv = rsqrtf(var + 1e-5f);
  const float4* g4 = (const float4*)gamma;
  const float4* b4 = (const float4*)beta;
  bf16_t* xo = xn + (long)tok * DM;
#pragma unroll
  for (int i = 0; i < 3; i++) {
    float4 v = (i == 0) ? v0 : (i == 1) ? v1 : v2;
    float4 g = g4[lane + 64 * i], b = b4[lane + 64 * i];
    bf16x4 o;
    o[0] = (bf16_t)((v.x - mu) * inv * g.x + b.x);
    o[1] = (bf16_t)((v.y - mu) * inv * g.y + b.y);
    o[2] = (bf16_t)((v.z - mu) * inv * g.z + b.z);
    o[3] = (bf16_t)((v.w - mu) * inv * g.w + b.w);
    *(bf16x4*)(xo + lane * 4 + i * 256) = o;
  }
}

// ---------------- depthwise causal conv (4 taps) + hs (token per wave) -------
__global__ __launch_bounds__(256)
void conv_kernel(const bf16_t* __restrict__ xz, const float* __restrict__ conv_w,
                 const float* __restrict__ a_vec, const float* __restrict__ b_vec,
                 bf16_t* __restrict__ x1, float* __restrict__ hs) {
  const int tok = blockIdx.x * 4 + (threadIdx.x >> 6);
  const int lane = threadIdx.x & 63;
  const int l = tok & (SEQ_LEN - 1);
  const bf16_t* base = xz + (long)tok * 1536;
  const float4* w4 = (const float4*)conv_w;
  float s = 0.f, sa = 0.f, sb = 0.f;

  // region 1: channels lane*8 .. lane*8+7 (512 channels)
  {
    const int c0 = lane * 8;
    bf16x8 cur = *(const bf16x8*)(base + c0);
    bf16x8 p1 = {}, p2 = {}, p3 = {};
    if (l >= 1) p1 = *(const bf16x8*)(base + c0 - 1536);
    if (l >= 2) p2 = *(const bf16x8*)(base + c0 - 2 * 1536);
    if (l >= 3) p3 = *(const bf16x8*)(base + c0 - 3 * 1536);
    bf16x8 o;
#pragma unroll
    for (int j = 0; j < 8; j++) {
      float4 w = w4[c0 + j];
      float acc = w.w * (float)cur[j] + w.z * (float)p1[j] +
                  w.y * (float)p2[j] + w.x * (float)p3[j];
      bf16_t xb = (bf16_t)acc;
      o[j] = xb;
      float xv = (float)xb;
      s += xv; sa += xv * a_vec[c0 + j]; sb += xv * b_vec[c0 + j];
    }
    *(bf16x8*)(x1 + (long)tok * DM + c0) = o;
  }
  // region 2: channels 512 + lane*4 .. +3 (256 channels)
  {
    const int c0 = 512 + lane * 4;
    bf16x4 cur = *(const bf16x4*)(base + c0);
    bf16x4 p1 = {}, p2 = {}, p3 = {};
    if (l >= 1) p1 = *(const bf16x4*)(base + c0 - 1536);
    if (l >= 2) p2 = *(const bf16x4*)(base + c0 - 2 * 1536);
    if (l >= 3) p3 = *(const bf16x4*)(base + c0 - 3 * 1536);
    bf16x4 o;
#pragma unroll
    for (int j = 0; j < 4; j++) {
      float4 w = w4[c0 + j];
      float acc = w.w * (float)cur[j] + w.z * (float)p1[j] +
                  w.y * (float)p2[j] + w.x * (float)p3[j];
      bf16_t xb = (bf16_t)acc;
      o[j] = xb;
      float xv = (float)xb;
      s += xv; sa += xv * a_vec[c0 + j]; sb += xv * b_vec[c0 + j];
    }
    *(bf16x4*)(x1 + (long)tok * DM + c0) = o;
  }
  for (int o = 1; o < 64; o <<= 1) {
    s += __shfl_xor(s, o); sa += __shfl_xor(sa, o); sb += __shfl_xor(sb, o);
  }
  if (lane == 0) hs[tok] = sa + s * sb;
}

// ---------------- 256x128 MFMA GEMM ----------------
// C[M,N] = A[M,K] @ BT[N,K]^T ; wave-tile 128x64, acc 8x4 of 16x16
// OUT_MODE 0: bf16 out
// OUT_MODE 1: fused SSM epilogue -> y bf16
// OUT_MODE 2: f32 out + residual add
template <int OUT_MODE>
__global__ __launch_bounds__(256, 2)
void gemm256_kernel(const bf16_t* __restrict__ A, const bf16_t* __restrict__ BT,
                    void* __restrict__ outp, const float* __restrict__ res,
                    const bf16_t* __restrict__ x1, const bf16_t* __restrict__ xz,
                    const float* __restrict__ hs, const float* __restrict__ Dp,
                    int M, int N, int K) {
  __shared__ __align__(16) bf16_t As[256 * 32];  // 16 KB
  __shared__ __align__(16) bf16_t Bs[128 * 32];  //  8 KB
  const int m0 = blockIdx.x * 256;
  const int n0 = blockIdx.y * 128;
  const int t = threadIdx.x;
  const int lane = t & 63;
  const int wave = t >> 6;
  const int wm = (wave >> 1) * 128;
  const int wn = (wave & 1) * 64;
  const int l15 = lane & 15;
  const int quad = lane >> 4;

  f32x4 acc[8][4] = {};

  // staging: 512-elem chunks (64 lanes x 16B). A: 16 chunks, B: 8 chunks.
  const int sr = lane >> 2;        // row within chunk (16 rows/chunk)
  const int sc = (lane & 3) * 8;   // k-col
  const bf16_t* Ag[4];
  bf16_t* lA[4];
#pragma unroll
  for (int i = 0; i < 4; i++) {
    int ch = wave * 4 + i;
    Ag[i] = A + (long)(m0 + ch * 16 + sr) * K + sc;
    lA[i] = As + ch * 512 + lane * 8;
  }
  const bf16_t* Bg[2];
  bf16_t* lB[2];
#pragma unroll
  for (int i = 0; i < 2; i++) {
    int ch = wave * 2 + i;
    Bg[i] = BT + (long)(n0 + ch * 16 + sr) * K + sc;
    lB[i] = Bs + ch * 512 + lane * 8;
  }

  for (int k0 = 0; k0 < K; k0 += 32) {
#pragma unroll
    for (int i = 0; i < 4; i++) load16_to_lds(Ag[i] + k0, lA[i]);
#pragma unroll
    for (int i = 0; i < 2; i++) load16_to_lds(Bg[i] + k0, lB[i]);
    __syncthreads();
    bf16x8 bfrag[4];
#pragma unroll
    for (int ni = 0; ni < 4; ni++)
      bfrag[ni] = *(const bf16x8*)&Bs[(wn + ni * 16 + l15) * 32 + quad * 8];
#pragma unroll
    for (int mi = 0; mi < 8; mi++) {
      bf16x8 afrag = *(const bf16x8*)&As[(wm + mi * 16 + l15) * 32 + quad * 8];
#pragma unroll
      for (int ni = 0; ni < 4; ni++)
        acc[mi][ni] = __builtin_amdgcn_mfma_f32_16x16x32_bf16(afrag, bfrag[ni], acc[mi][ni], 0, 0, 0);
    }
    __syncthreads();
  }

#pragma unroll
  for (int mi = 0; mi < 8; mi++) {
#pragma unroll
    for (int r = 0; r < 4; r++) {
      const int row = m0 + wm + mi * 16 + quad * 4 + r;
      float hsv = 0.f;
      if (OUT_MODE == 1) hsv = hs[row];
#pragma unroll
      for (int ni = 0; ni < 4; ni++) {
        const int col = n0 + wn + ni * 16 + l15;
        const long o = (long)row * N + col;
        float v = acc[mi][ni][r];
        if (OUT_MODE == 0) {
          ((bf16_t*)outp)[o] = (bf16_t)v;
        } else if (OUT_MODE == 1) {
          float xv = (float)x1[(long)row * DM + col];
          float zv = (float)xz[(long)row * 1536 + DM + col];
          float yv = v * hsv + Dp[col] * xv;
          yv *= zv / (1.f + __expf(-zv));
          ((bf16_t*)outp)[o] = (bf16_t)yv;
        } else {
          ((float*)outp)[o] = v + res[o];
        }
      }
    }
  }
}

// ---------------- launch ----------------
extern "C" void kernel_launch(void* const* d_in, const int* in_sizes, int n_in,
                              void* d_out, int out_size, void* d_ws, size_t ws_size,
                              hipStream_t stream) {
  const float* x      = (const float*)d_in[0];
  const float* W_in   = (const float*)d_in[1];
  const float* conv_w = (const float*)d_in[2];
  const float* W_x    = (const float*)d_in[3];
  const float* A_log  = (const float*)d_in[4];
  const float* Dp     = (const float*)d_in[5];
  const float* W_out  = (const float*)d_in[6];
  const float* gamma  = (const float*)d_in[7];
  const float* beta   = (const float*)d_in[8];
  float* out = (float*)d_out;

  char* ws = (char*)d_ws;
  bf16_t* w_in_T  = (bf16_t*)(ws + 0);          // 1536x768 bf16
  bf16_t* w_c_T   = (bf16_t*)(ws + 2359296);    //  768x768 bf16
  bf16_t* w_out_T = (bf16_t*)(ws + 3538944);    //  768x768 bf16
  float*  a_vec   = (float*)(ws + 4718592);
  float*  b_vec   = (float*)(ws + 4721664);
  float*  hs      = (float*)(ws + 4724736);     // 32768 f32
  bf16_t* xn      = (bf16_t*)(ws + 4855808);    // 32768x768 bf16 (reused as y)
  bf16_t* xz      = (bf16_t*)(ws + 55187456);   // 32768x1536 bf16
  bf16_t* x1      = (bf16_t*)(ws + 155850752);  // 32768x768 bf16
  bf16_t* y       = xn;

  cast_transpose_kernel<<<dim3(1536 * 768 / 256), 256, 0, stream>>>(W_in, w_in_T, 768, 1536, 1536, 0);
  cast_transpose_kernel<<<dim3(768 * 768 / 256), 256, 0, stream>>>(W_x, w_c_T, 768, 768, 784, 16);
  cast_transpose_kernel<<<dim3(768 * 768 / 256), 256, 0, stream>>>(W_out, w_out_T, 768, 768, 768, 0);
  ab_kernel<<<dim3(3), 256, 0, stream>>>(W_x, A_log, a_vec, b_vec);

  ln_kernel<<<dim3(TOKENS / 4), 256, 0, stream>>>(x, gamma, beta, xn);

  gemm256_kernel<0><<<dim3(TOKENS / 256, 1536 / 128), 256, 0, stream>>>(
      xn, w_in_T, (void*)xz, nullptr, nullptr, nullptr, nullptr, nullptr,
      TOKENS, 1536, 768);

  conv_kernel<<<dim3(TOKENS / 4), 256, 0, stream>>>(xz, conv_w, a_vec, b_vec, x1, hs);

  gemm256_kernel<1><<<dim3(TOKENS / 256, 768 / 128), 256, 0, stream>>>(
      x1, w_c_T, (void*)y, nullptr, x1, xz, hs, Dp,
      TOKENS, 768, 768);

  gemm256_kernel<2><<<dim3(TOKENS / 256, 768 / 128), 256, 0, stream>>>(
      y, w_out_T, (void*)out, x, nullptr, nullptr, nullptr, nullptr,
      TOKENS, 768, 768);
}